// Round 5
// baseline (120.144 us; speedup 1.0000x reference)
//
#include <hip/hip_runtime.h>
#include <stdint.h>

typedef __attribute__((ext_vector_type(8))) short short8;
typedef __attribute__((ext_vector_type(4))) float f32x4;
typedef __attribute__((ext_vector_type(16))) float f32x16;
typedef unsigned long long u64;

#define BB 8
#define CC 256
#define PP 1024
#define NH 4
#define DH 64

// q-scale: dh^-0.5 * log2(e), so softmax can use raw v_exp (exp2)
#define QSCALE 0.18033688f

__device__ __forceinline__ unsigned short f2bf(float f) {
  union { float f; unsigned u; } v; v.f = f;
  unsigned r = v.u + 0x7FFFu + ((v.u >> 16) & 1u);
  return (unsigned short)(r >> 16);
}

__device__ __forceinline__ f32x4 mfma16(short8 a, short8 b, f32x4 c) {
  return __builtin_amdgcn_mfma_f32_16x16x32_bf16(a, b, c, 0, 0, 0);
}
__device__ __forceinline__ f32x16 mfma32(short8 a, short8 b, f32x16 c) {
  return __builtin_amdgcn_mfma_f32_32x32x16_bf16(a, b, c, 0, 0, 0);
}

// -------- Kernel 1: GroupNorm partial sums (512 blk) + weight cvt (256 blk) -
__global__ __launch_bounds__(256) void prep(
    const float* __restrict__ x, float2* __restrict__ part,
    const float* __restrict__ qkvw, const float* __restrict__ projw,
    unsigned short* __restrict__ wall) {
  int blk = blockIdx.x;
  int tid = threadIdx.x;
  if (blk < 512) {
    int sl = blk & 7, g = (blk >> 3) & 7, b = blk >> 6;
    const float4* xb =
        (const float4*)(x + (size_t)(b * CC + g * 32) * PP) + sl * 1024;
    float s = 0.f, q = 0.f;
    for (int i = tid; i < 1024; i += 256) {
      float4 v = xb[i];
      s += v.x + v.y + v.z + v.w;
      q += v.x * v.x + v.y * v.y + v.z * v.z + v.w * v.w;
    }
    for (int off = 32; off > 0; off >>= 1) {
      s += __shfl_down(s, off);
      q += __shfl_down(q, off);
    }
    __shared__ float rs[4], rq[4];
    int w = tid >> 6;
    if ((tid & 63) == 0) { rs[w] = s; rq[w] = q; }
    __syncthreads();
    if (tid == 0)
      part[blk] = make_float2(rs[0] + rs[1] + rs[2] + rs[3],
                              rq[0] + rq[1] + rq[2] + rq[3]);
  } else {
    int i4 = (blk - 512) * 256 + tid;  // 65536 float4s total
    float4 v = (i4 < 49152) ? ((const float4*)qkvw)[i4]
                            : ((const float4*)projw)[i4 - 49152];
    ushort4 o;
    o.x = f2bf(v.x); o.y = f2bf(v.y); o.z = f2bf(v.z); o.w = f2bf(v.w);
    ((ushort4*)wall)[i4] = o;
  }
}

// ------------- Kernel 2: fused GroupNorm + QKV GEMM ------------------------
// Tile 64p x 128o -> grid 768 = exactly 3 blocks/CU; launch_bounds(256,3).
// Decode keeps the 6 o-tiles sharing one (p0,b) x-slice on the SAME XCD.
// A_l padded to 42 shorts/row: ds_write_b16 transpose is bank-conflict-free.
__global__ __launch_bounds__(256, 3) void nqkv(
    const float* __restrict__ x, const float2* __restrict__ part,
    const float* __restrict__ gamma, const float* __restrict__ beta,
    const unsigned short* __restrict__ wbf, const float* __restrict__ qkvb,
    unsigned short* __restrict__ qb, unsigned short* __restrict__ kb,
    unsigned short* __restrict__ vT) {
  int bid = blockIdx.x;
  int c8 = bid & 7, rr = bid >> 3;       // rr: 0..95
  int t = rr % 6, base = rr / 6;         // t: o-tile, base: 0..15
  int p0 = base * 64, b = c8, o0 = t * 128;
  int tid = threadIdx.x;
  int w = tid >> 6, lane = tid & 63, lq = lane >> 4, ln = lane & 15;
  int wy = w >> 1, wx = w & 1;
  __shared__ unsigned short A_l[64][42];
  __shared__ unsigned short B_l[128][40];
  __shared__ float scs[256], shs[256];
  __shared__ float g_m[8], g_r[8];
  if (tid < 8) {
    float S = 0.f, Q = 0.f;
    for (int i = 0; i < 8; ++i) {
      float2 pp = part[b * 64 + tid * 8 + i];
      S += pp.x; Q += pp.y;
    }
    float mean = S * (1.f / 32768.f);
    float var = Q * (1.f / 32768.f) - mean * mean;
    g_m[tid] = mean;
    g_r[tid] = rsqrtf(var + 1e-5f);
  }
  __syncthreads();
  {
    int c = tid;
    float sc = g_r[c >> 5] * gamma[c];
    scs[c] = sc;
    shs[c] = beta[c] - g_m[c >> 5] * sc;
  }
  __syncthreads();
  f32x4 acc[2][4];
  for (int i = 0; i < 2; ++i)
    for (int j = 0; j < 4; ++j) acc[i][j] = (f32x4){0.f, 0.f, 0.f, 0.f};
  int cc = tid >> 3, ps = tid & 7;
  for (int kc = 0; kc < 256; kc += 32) {
    // A stage: 32 c-rows x 64 p, fp32 -> normalize -> bf16 -> transpose
    {
      float sc = scs[kc + cc], sh = shs[kc + cc];
      const float* xr = x + ((size_t)(b * CC + kc + cc)) * PP + p0;
#pragma unroll
      for (int i = 0; i < 2; ++i) {
        int p = ps * 4 + 32 * i;
        float4 v = *(const float4*)(xr + p);
        A_l[p + 0][cc] = f2bf(v.x * sc + sh);
        A_l[p + 1][cc] = f2bf(v.y * sc + sh);
        A_l[p + 2][cc] = f2bf(v.z * sc + sh);
        A_l[p + 3][cc] = f2bf(v.w * sc + sh);
      }
    }
    // B stage: 128 o-rows x 32 c bf16 weights
    for (int it = 0; it < 2; ++it) {
      int l = tid + 256 * it;
      int row = l >> 2, seg = l & 3;
      *(short8*)&B_l[row][seg * 8] =
          *(const short8*)(wbf + (size_t)(o0 + row) * CC + kc + seg * 8);
    }
    __syncthreads();
    short8 af[2], bfr[4];
    for (int i = 0; i < 2; ++i)
      af[i] = *(const short8*)&A_l[wy * 32 + i * 16 + ln][lq * 8];
    for (int j = 0; j < 4; ++j)
      bfr[j] = *(const short8*)&B_l[wx * 64 + j * 16 + ln][lq * 8];
    for (int i = 0; i < 2; ++i)
      for (int j = 0; j < 4; ++j) acc[i][j] = mfma16(af[i], bfr[j], acc[i][j]);
    __syncthreads();
  }
  for (int i = 0; i < 2; ++i) {
    for (int j = 0; j < 4; ++j) {
      int o = o0 + wx * 64 + j * 16 + ln;
      int s = o >> 8, h = (o >> 6) & 3, ch = o & 63;
      float bias = qkvb[o];
      float mul = (s == 0) ? QSCALE : 1.0f;
      size_t bh = (size_t)b * NH + h;
      int pbase = p0 + wy * 32 + i * 16 + lq * 4;
      if (s == 2) {
        union { unsigned short u[4]; u64 ll; } pk;
#pragma unroll
        for (int r = 0; r < 4; ++r) pk.u[r] = f2bf(acc[i][j][r] + bias);
        *(u64*)(vT + (bh * DH + ch) * PP + pbase) = pk.ll;
      } else {
        unsigned short* dst = (s == 0) ? qb : kb;
#pragma unroll
        for (int r = 0; r < 4; ++r)
          dst[(bh * PP + pbase + r) * DH + ch] =
              f2bf((acc[i][j][r] + bias) * mul);
      }
    }
  }
}

// ------------- Kernel 3: flash attention, 32x32 MFMA -----------------------
// d-tile 32 -> grid 1024 = 4 blocks/CU = 4 waves/SIMD (was 512 = 2/CU; grid
// was the occupancy limiter, barrier/vmcnt drains exposed at 2 waves/SIMD).
// 4 waves = 4 e-slices of 32 per 128-e iter; per-tile QK/softmax/PV math
// identical (tile index = we). 4-way cross-wave O/l reduce at end via LDS
// (Ored reuses K/V LDS after last barrier). Same-XCD decode: 32 d-tiles
// sharing one (h,b) K/V pinned to one XCD L2.
__global__ __launch_bounds__(256, 4) void attn(
    const unsigned short* __restrict__ qb, const unsigned short* __restrict__ kb,
    const unsigned short* __restrict__ vT, unsigned short* __restrict__ attnT) {
  int bid = blockIdx.x;
  int c8 = bid & 7, rr = bid >> 3;   // rr: 0..127
  int t32 = rr & 31, base = rr >> 5; // t32: d-tile, base: 0..3
  int g = base * 8 + c8;             // 0..31 (h,b) group, same XCD
  int h = g & 3, b = g >> 2;
  int d0 = t32 * 32;
  int tid = threadIdx.x;
  int we = tid >> 6, lane = tid & 63;
  int n = lane & 31, hi = lane >> 5;
  size_t bh = (size_t)b * NH + h;
  const unsigned short* qbase = qb + bh * PP * DH;
  const unsigned short* kbase = kb + bh * PP * DH;
  const unsigned short* vbase = vT + bh * DH * PP;

  __shared__ __align__(16) char smem[32768];
  unsigned short* K_ls = (unsigned short*)smem;            // [128][64] swz
  unsigned short* V_ls = (unsigned short*)(smem + 16384);  // [64][128] swz
  float* Ored = (float*)smem;                              // [3][64][33]
  float* lsred = (float*)(smem + 25344);                   // [96]
  unsigned short* O_l = (unsigned short*)(smem + 25728);   // [32][72]

#define KIDX(e, cb) ((e) * 64 + (((cb) ^ ((e) & 7)) << 3))
#define VIDX(ch, cb, off) ((ch) * 128 + (((cb) ^ ((ch) & 7)) << 3) + (off))

  int ke = tid >> 1, kseg = tid & 1;   // K: 128 rows x 2 half-rows
  int vch = tid >> 2, vseg = tid & 3;  // V: 64 rows x 4 quarter-rows

  short8 qf[4];
  {
    int dq = d0 + n;
#pragma unroll
    for (int kc = 0; kc < 4; ++kc)
      qf[kc] = *(const short8*)(qbase + (size_t)dq * DH + kc * 16 + hi * 8);
  }
  float l_sum = 0.f;
  f32x16 o_acc[2];
#pragma unroll
  for (int i = 0; i < 16; ++i) { o_acc[0][i] = 0.f; o_acc[1][i] = 0.f; }

  short8 kr[4], vr[4];
#pragma unroll
  for (int i = 0; i < 4; ++i)
    kr[i] = *(const short8*)(kbase + (size_t)ke * DH + kseg * 32 + i * 8);
#pragma unroll
  for (int i = 0; i < 4; ++i)
    vr[i] = *(const short8*)(vbase + (size_t)vch * PP + vseg * 32 + i * 8);

  for (int e0 = 0; e0 < PP; e0 += 128) {
#pragma unroll
    for (int i = 0; i < 4; ++i)
      *(short8*)&K_ls[KIDX(ke, kseg * 4 + i)] = kr[i];
#pragma unroll
    for (int i = 0; i < 4; ++i) {
      int acb = vseg * 4 + i;     // actual 8-col chunk (0..15)
      int blkA = acb >> 1;        // 16-col block
      int h8 = acb & 1;
      union { short8 v; u64 q[2]; } uv; uv.v = vr[i];
      *(u64*)&V_ls[VIDX(vch, blkA * 2 + 0, h8 * 4)] = uv.q[0];
      *(u64*)&V_ls[VIDX(vch, blkA * 2 + 1, h8 * 4)] = uv.q[1];
    }
    if (e0 + 128 < PP) {
      int en = e0 + 128;
#pragma unroll
      for (int i = 0; i < 4; ++i)
        kr[i] = *(const short8*)(kbase + (size_t)(en + ke) * DH + kseg * 32 + i * 8);
#pragma unroll
      for (int i = 0; i < 4; ++i)
        vr[i] = *(const short8*)(vbase + (size_t)vch * PP + en + vseg * 32 + i * 8);
    }
    __syncthreads();
    // ---- QK^T (S^T): this wave's 32-e tile (tile index = we) ----
    u64 pk[4];
    {
      f32x16 s;
#pragma unroll
      for (int i = 0; i < 16; ++i) s[i] = 0.f;
      int erow = we * 32 + n;
#pragma unroll
      for (int kc = 0; kc < 4; ++kc) {
        short8 af = *(const short8*)&K_ls[KIDX(erow, kc * 2 + hi)];
        s = mfma32(af, qf[kc], s);
      }
#pragma unroll
      for (int gg = 0; gg < 4; ++gg) {
        float p0 = __builtin_amdgcn_exp2f(fminf(s[4 * gg + 0], 86.f));
        float p1 = __builtin_amdgcn_exp2f(fminf(s[4 * gg + 1], 86.f));
        float p2 = __builtin_amdgcn_exp2f(fminf(s[4 * gg + 2], 86.f));
        float p3 = __builtin_amdgcn_exp2f(fminf(s[4 * gg + 3], 86.f));
        l_sum += (p0 + p1) + (p2 + p3);
        union { unsigned short u[4]; u64 ll; } pkk;
        pkk.u[0] = f2bf(p0); pkk.u[1] = f2bf(p1);
        pkk.u[2] = f2bf(p2); pkk.u[3] = f2bf(p3);
        pk[gg] = pkk.ll;
      }
    }
    // ---- PV: O[ch][d] += V_sigma * P (P fragment = own regs) ----
#pragma unroll
    for (int c = 0; c < 2; ++c) {
      union { u64 q[2]; short8 v; } pf;
      pf.q[0] = pk[2 * c];
      pf.q[1] = pk[2 * c + 1];
      int cb = we * 4 + c * 2 + hi;
#pragma unroll
      for (int mt = 0; mt < 2; ++mt) {
        int ch = mt * 32 + n;
        short8 af = *(const short8*)&V_ls[VIDX(ch, cb, 0)];
        o_acc[mt] = mfma32(af, pf.v, o_acc[mt]);
      }
    }
    __syncthreads();
  }
  // ---- cross-hi row-sum, then 4-way cross-we reduce via LDS ----
  l_sum += __shfl_xor(l_sum, 32);
  if (we != 0) {
    if (hi == 0) lsred[(we - 1) * 32 + n] = l_sum;
#pragma unroll
    for (int mt = 0; mt < 2; ++mt)
#pragma unroll
      for (int r = 0; r < 16; ++r) {
        int chl = (r & 3) + 8 * (r >> 2) + 4 * hi;
        Ored[((we - 1) * 64 + mt * 32 + chl) * 33 + n] = o_acc[mt][r];
      }
  }
  __syncthreads();
  if (we == 0) {
    float inv = 1.f / (l_sum + lsred[n] + lsred[32 + n] + lsred[64 + n]);
#pragma unroll
    for (int mt = 0; mt < 2; ++mt) {
#pragma unroll
      for (int gg = 0; gg < 4; ++gg) {
        union { unsigned short u[4]; u64 ll; } pkk;
#pragma unroll
        for (int q = 0; q < 4; ++q) {
          int r = gg * 4 + q;
          int chl = q + 8 * gg + 4 * hi;
          float v = o_acc[mt][r] + Ored[(mt * 32 + chl) * 33 + n] +
                    Ored[(64 + mt * 32 + chl) * 33 + n] +
                    Ored[(128 + mt * 32 + chl) * 33 + n];
          pkk.u[q] = f2bf(v * inv);
        }
        *(u64*)&O_l[n * 72 + mt * 32 + gg * 8 + 4 * hi] = pkk.ll;
      }
    }
  }
  __syncthreads();
  {
    int dd = tid >> 3, seg = tid & 7;
    *(short8*)(attnT + ((size_t)b * PP + d0 + dd) * CC + h * DH + seg * 8) =
        *(const short8*)&O_l[dd * 72 + seg * 8];
  }
#undef KIDX
#undef VIDX
}

// ------------- Kernel 4: proj GEMM + bias + residual (fp32 out) ------------
// Tile 32p x 64o -> grid 1024 = 4 blocks/CU (was 512 = 2/CU; memory-bound
// streaming kernel needs waves to hide HBM latency). Waves: (o-half 32) x
// (p-half 16). Same-XCD decode for the 8 tiles sharing one (p0,b) slice.
__global__ __launch_bounds__(256) void proj_gemm(
    const unsigned short* __restrict__ attnT, const unsigned short* __restrict__ pwbf,
    const float* __restrict__ projb, const float* __restrict__ x,
    float* __restrict__ out) {
  int bid = blockIdx.x;
  int c8 = bid & 7, rr = bid >> 3;   // rr: 0..127
  int t = rr & 3, base = rr >> 2;    // t: o-tile, base: 0..31
  int p0 = base * 32, b = c8, o0 = t * 64;
  int tid = threadIdx.x;
  int w = tid >> 6, lane = tid & 63, lq = lane >> 4, ln = lane & 15;
  int wo = w >> 1, wp = w & 1;
  __shared__ unsigned short A_l[64][40];
  __shared__ unsigned short B_l[32][40];
  f32x4 acc[2];
  for (int i = 0; i < 2; ++i) acc[i] = (f32x4){0.f, 0.f, 0.f, 0.f};
  for (int kc = 0; kc < 256; kc += 32) {
    {
      int row = tid >> 2, seg = tid & 3;
      *(short8*)&A_l[row][seg * 8] =
          *(const short8*)(pwbf + (size_t)(o0 + row) * CC + kc + seg * 8);
      if (tid < 128)
        *(short8*)&B_l[row][seg * 8] =
            *(const short8*)(attnT + ((size_t)b * PP + p0 + row) * CC + kc + seg * 8);
    }
    __syncthreads();
    short8 af[2];
    for (int i = 0; i < 2; ++i)
      af[i] = *(const short8*)&A_l[wo * 32 + i * 16 + ln][lq * 8];
    short8 bfr = *(const short8*)&B_l[wp * 16 + ln][lq * 8];
    for (int i = 0; i < 2; ++i) acc[i] = mfma16(af[i], bfr, acc[i]);
    __syncthreads();
  }
  int p = p0 + wp * 16 + ln;
  for (int i = 0; i < 2; ++i) {
    for (int r = 0; r < 4; ++r) {
      int o = o0 + wo * 32 + i * 16 + lq * 4 + r;
      size_t idx = ((size_t)b * CC + o) * PP + p;
      out[idx] = x[idx] + projb[o] + acc[i][r];
    }
  }
}

// ---------------------------------------------------------------------------
extern "C" void kernel_launch(void* const* d_in, const int* in_sizes, int n_in,
                              void* d_out, int out_size, void* d_ws, size_t ws_size,
                              hipStream_t stream) {
  const float* x = (const float*)d_in[0];
  const float* gamma = (const float*)d_in[1];
  const float* beta = (const float*)d_in[2];
  const float* qkvw = (const float*)d_in[3];
  const float* qkvb = (const float*)d_in[4];
  const float* projw = (const float*)d_in[5];
  const float* projb = (const float*)d_in[6];
  float* out = (float*)d_out;
  char* ws = (char*)d_ws;

  float2* part = (float2*)(ws + 0);                        //  4 KB
  unsigned short* wall = (unsigned short*)(ws + 4210688);  // 512 KB
  unsigned short* pwbf = wall + 768 * 256;
  unsigned short* qb = (unsigned short*)(ws + 4734976);      // 4 MB
  unsigned short* kb = (unsigned short*)(ws + 8929280);      // 4 MB
  unsigned short* vT = (unsigned short*)(ws + 13123584);     // 4 MB
  unsigned short* attnT = (unsigned short*)(ws + 17317888);  // 4 MB

  prep<<<768, 256, 0, stream>>>(x, part, qkvw, projw, wall);
  nqkv<<<768, 256, 0, stream>>>(x, part, gamma, beta, wall, qkvb, qb, kb, vT);
  attn<<<1024, 256, 0, stream>>>(qb, kb, vT, attnT);
  proj_gemm<<<1024, 256, 0, stream>>>(attnT, pwbf, projb, x, out);
}

// Round 6
// 114.912 us; speedup vs baseline: 1.0455x; 1.0455x over previous
//
#include <hip/hip_runtime.h>
#include <stdint.h>

typedef __attribute__((ext_vector_type(8))) short short8;
typedef __attribute__((ext_vector_type(4))) float f32x4;
typedef __attribute__((ext_vector_type(16))) float f32x16;
typedef unsigned long long u64;

#define BB 8
#define CC 256
#define PP 1024
#define NH 4
#define DH 64

// q-scale: dh^-0.5 * log2(e), so softmax can use raw v_exp (exp2)
#define QSCALE 0.18033688f

__device__ __forceinline__ unsigned short f2bf(float f) {
  union { float f; unsigned u; } v; v.f = f;
  unsigned r = v.u + 0x7FFFu + ((v.u >> 16) & 1u);
  return (unsigned short)(r >> 16);
}

__device__ __forceinline__ f32x4 mfma16(short8 a, short8 b, f32x4 c) {
  return __builtin_amdgcn_mfma_f32_16x16x32_bf16(a, b, c, 0, 0, 0);
}
__device__ __forceinline__ f32x16 mfma32(short8 a, short8 b, f32x16 c) {
  return __builtin_amdgcn_mfma_f32_32x32x16_bf16(a, b, c, 0, 0, 0);
}

// -------- Kernel 1: GroupNorm partial sums (512 blk) + weight cvt (256 blk) -
__global__ __launch_bounds__(256) void prep(
    const float* __restrict__ x, float2* __restrict__ part,
    const float* __restrict__ qkvw, const float* __restrict__ projw,
    unsigned short* __restrict__ wall) {
  int blk = blockIdx.x;
  int tid = threadIdx.x;
  if (blk < 512) {
    int sl = blk & 7, g = (blk >> 3) & 7, b = blk >> 6;
    const float4* xb =
        (const float4*)(x + (size_t)(b * CC + g * 32) * PP) + sl * 1024;
    float s = 0.f, q = 0.f;
    for (int i = tid; i < 1024; i += 256) {
      float4 v = xb[i];
      s += v.x + v.y + v.z + v.w;
      q += v.x * v.x + v.y * v.y + v.z * v.z + v.w * v.w;
    }
    for (int off = 32; off > 0; off >>= 1) {
      s += __shfl_down(s, off);
      q += __shfl_down(q, off);
    }
    __shared__ float rs[4], rq[4];
    int w = tid >> 6;
    if ((tid & 63) == 0) { rs[w] = s; rq[w] = q; }
    __syncthreads();
    if (tid == 0)
      part[blk] = make_float2(rs[0] + rs[1] + rs[2] + rs[3],
                              rq[0] + rq[1] + rq[2] + rq[3]);
  } else {
    int i4 = (blk - 512) * 256 + tid;  // 65536 float4s total
    float4 v = (i4 < 49152) ? ((const float4*)qkvw)[i4]
                            : ((const float4*)projw)[i4 - 49152];
    ushort4 o;
    o.x = f2bf(v.x); o.y = f2bf(v.y); o.z = f2bf(v.z); o.w = f2bf(v.w);
    ((ushort4*)wall)[i4] = o;
  }
}

// ------------- Kernel 2: fused GroupNorm + QKV GEMM ------------------------
// Tile 64p x 128o -> grid 768 = exactly 3 blocks/CU; launch_bounds(256,3).
// Decode keeps the 6 o-tiles sharing one (p0,b) x-slice on the SAME XCD.
// A_l padded to 42 shorts/row: ds_write_b16 transpose is bank-conflict-free.
__global__ __launch_bounds__(256, 3) void nqkv(
    const float* __restrict__ x, const float2* __restrict__ part,
    const float* __restrict__ gamma, const float* __restrict__ beta,
    const unsigned short* __restrict__ wbf, const float* __restrict__ qkvb,
    unsigned short* __restrict__ qb, unsigned short* __restrict__ kb,
    unsigned short* __restrict__ vT) {
  int bid = blockIdx.x;
  int c8 = bid & 7, rr = bid >> 3;       // rr: 0..95
  int t = rr % 6, base = rr / 6;         // t: o-tile, base: 0..15
  int p0 = base * 64, b = c8, o0 = t * 128;
  int tid = threadIdx.x;
  int w = tid >> 6, lane = tid & 63, lq = lane >> 4, ln = lane & 15;
  int wy = w >> 1, wx = w & 1;
  __shared__ unsigned short A_l[64][42];
  __shared__ unsigned short B_l[128][40];
  __shared__ float scs[256], shs[256];
  __shared__ float g_m[8], g_r[8];
  if (tid < 8) {
    float S = 0.f, Q = 0.f;
    for (int i = 0; i < 8; ++i) {
      float2 pp = part[b * 64 + tid * 8 + i];
      S += pp.x; Q += pp.y;
    }
    float mean = S * (1.f / 32768.f);
    float var = Q * (1.f / 32768.f) - mean * mean;
    g_m[tid] = mean;
    g_r[tid] = rsqrtf(var + 1e-5f);
  }
  __syncthreads();
  {
    int c = tid;
    float sc = g_r[c >> 5] * gamma[c];
    scs[c] = sc;
    shs[c] = beta[c] - g_m[c >> 5] * sc;
  }
  __syncthreads();
  f32x4 acc[2][4];
  for (int i = 0; i < 2; ++i)
    for (int j = 0; j < 4; ++j) acc[i][j] = (f32x4){0.f, 0.f, 0.f, 0.f};
  int cc = tid >> 3, ps = tid & 7;
  for (int kc = 0; kc < 256; kc += 32) {
    // A stage: 32 c-rows x 64 p, fp32 -> normalize -> bf16 -> transpose
    {
      float sc = scs[kc + cc], sh = shs[kc + cc];
      const float* xr = x + ((size_t)(b * CC + kc + cc)) * PP + p0;
#pragma unroll
      for (int i = 0; i < 2; ++i) {
        int p = ps * 4 + 32 * i;
        float4 v = *(const float4*)(xr + p);
        A_l[p + 0][cc] = f2bf(v.x * sc + sh);
        A_l[p + 1][cc] = f2bf(v.y * sc + sh);
        A_l[p + 2][cc] = f2bf(v.z * sc + sh);
        A_l[p + 3][cc] = f2bf(v.w * sc + sh);
      }
    }
    // B stage: 128 o-rows x 32 c bf16 weights
    for (int it = 0; it < 2; ++it) {
      int l = tid + 256 * it;
      int row = l >> 2, seg = l & 3;
      *(short8*)&B_l[row][seg * 8] =
          *(const short8*)(wbf + (size_t)(o0 + row) * CC + kc + seg * 8);
    }
    __syncthreads();
    short8 af[2], bfr[4];
    for (int i = 0; i < 2; ++i)
      af[i] = *(const short8*)&A_l[wy * 32 + i * 16 + ln][lq * 8];
    for (int j = 0; j < 4; ++j)
      bfr[j] = *(const short8*)&B_l[wx * 64 + j * 16 + ln][lq * 8];
    for (int i = 0; i < 2; ++i)
      for (int j = 0; j < 4; ++j) acc[i][j] = mfma16(af[i], bfr[j], acc[i][j]);
    __syncthreads();
  }
  for (int i = 0; i < 2; ++i) {
    for (int j = 0; j < 4; ++j) {
      int o = o0 + wx * 64 + j * 16 + ln;
      int s = o >> 8, h = (o >> 6) & 3, ch = o & 63;
      float bias = qkvb[o];
      float mul = (s == 0) ? QSCALE : 1.0f;
      size_t bh = (size_t)b * NH + h;
      int pbase = p0 + wy * 32 + i * 16 + lq * 4;
      if (s == 2) {
        union { unsigned short u[4]; u64 ll; } pk;
#pragma unroll
        for (int r = 0; r < 4; ++r) pk.u[r] = f2bf(acc[i][j][r] + bias);
        *(u64*)(vT + (bh * DH + ch) * PP + pbase) = pk.ll;
      } else {
        unsigned short* dst = (s == 0) ? qb : kb;
#pragma unroll
        for (int r = 0; r < 4; ++r)
          dst[(bh * PP + pbase + r) * DH + ch] =
              f2bf((acc[i][j][r] + bias) * mul);
      }
    }
  }
}

// ------------- Kernel 3: flash attention, 32x32 MFMA -----------------------
// d-tile 64, grid 512 (2 blocks/CU) — measured optimum: smaller d-tiles
// double K/V staging traffic (r5 regression), larger tiles starve occupancy.
// Decode keeps the 16 d-tiles sharing one (h,b) K/V (256 KB) on the SAME
// XCD -> 16x K/V re-reads served from that L2.
__global__ __launch_bounds__(256, 2) void attn(
    const unsigned short* __restrict__ qb, const unsigned short* __restrict__ kb,
    const unsigned short* __restrict__ vT, unsigned short* __restrict__ attnT) {
  int bid = blockIdx.x;
  int c8 = bid & 7, rr = bid >> 3;   // rr: 0..63
  int t16 = rr & 15, base = rr >> 4; // t16: d-tile, base: 0..3
  int g = base * 8 + c8;             // 0..31 (h,b) group, same XCD
  int h = g & 3, b = g >> 2;
  int d0 = t16 * 64;
  int tid = threadIdx.x;
  int w = tid >> 6, lane = tid & 63;
  int n = lane & 31, hi = lane >> 5;
  int wd = w & 1, we = w >> 1;
  size_t bh = (size_t)b * NH + h;
  const unsigned short* qbase = qb + bh * PP * DH;
  const unsigned short* kbase = kb + bh * PP * DH;
  const unsigned short* vbase = vT + bh * DH * PP;

  __shared__ __align__(16) char smem[32768];
  unsigned short* K_ls = (unsigned short*)smem;            // [128][64] swz
  unsigned short* V_ls = (unsigned short*)(smem + 16384);  // [64][128] swz
  float* Ored = (float*)smem;                              // [128][34]
  float* lsred = (float*)(smem + 17408);                   // [64]
  unsigned short* O_l = (unsigned short*)(smem + 17664);   // [64][72]

#define KIDX(e, cb) ((e) * 64 + (((cb) ^ ((e) & 7)) << 3))
#define VIDX(ch, cb, off) ((ch) * 128 + (((cb) ^ ((ch) & 7)) << 3) + (off))

  int ke = tid >> 1, kseg = tid & 1;   // K: 128 rows x 2 half-rows
  int vch = tid >> 2, vseg = tid & 3;  // V: 64 rows x 4 quarter-rows

  short8 qf[4];
  {
    int dq = d0 + wd * 32 + n;
#pragma unroll
    for (int kc = 0; kc < 4; ++kc)
      qf[kc] = *(const short8*)(qbase + (size_t)dq * DH + kc * 16 + hi * 8);
  }
  float l_sum = 0.f;
  f32x16 o_acc[2];
#pragma unroll
  for (int i = 0; i < 16; ++i) { o_acc[0][i] = 0.f; o_acc[1][i] = 0.f; }

  short8 kr[4], vr[4];
#pragma unroll
  for (int i = 0; i < 4; ++i)
    kr[i] = *(const short8*)(kbase + (size_t)ke * DH + kseg * 32 + i * 8);
#pragma unroll
  for (int i = 0; i < 4; ++i)
    vr[i] = *(const short8*)(vbase + (size_t)vch * PP + vseg * 32 + i * 8);

  for (int e0 = 0; e0 < PP; e0 += 128) {
#pragma unroll
    for (int i = 0; i < 4; ++i)
      *(short8*)&K_ls[KIDX(ke, kseg * 4 + i)] = kr[i];
#pragma unroll
    for (int i = 0; i < 4; ++i) {
      int acb = vseg * 4 + i;     // actual 8-col chunk (0..15)
      int blkA = acb >> 1;        // 16-col block
      int h8 = acb & 1;
      union { short8 v; u64 q[2]; } uv; uv.v = vr[i];
      *(u64*)&V_ls[VIDX(vch, blkA * 2 + 0, h8 * 4)] = uv.q[0];
      *(u64*)&V_ls[VIDX(vch, blkA * 2 + 1, h8 * 4)] = uv.q[1];
    }
    if (e0 + 128 < PP) {
      int en = e0 + 128;
#pragma unroll
      for (int i = 0; i < 4; ++i)
        kr[i] = *(const short8*)(kbase + (size_t)(en + ke) * DH + kseg * 32 + i * 8);
#pragma unroll
      for (int i = 0; i < 4; ++i)
        vr[i] = *(const short8*)(vbase + (size_t)vch * PP + en + vseg * 32 + i * 8);
    }
    __syncthreads();
    u64 pk[2][4];
#pragma unroll
    for (int t = 0; t < 2; ++t) {
      f32x16 s;
#pragma unroll
      for (int i = 0; i < 16; ++i) s[i] = 0.f;
      int erow = we * 64 + t * 32 + n;
#pragma unroll
      for (int kc = 0; kc < 4; ++kc) {
        short8 af = *(const short8*)&K_ls[KIDX(erow, kc * 2 + hi)];
        s = mfma32(af, qf[kc], s);
      }
#pragma unroll
      for (int gg = 0; gg < 4; ++gg) {
        float p0 = __builtin_amdgcn_exp2f(fminf(s[4 * gg + 0], 86.f));
        float p1 = __builtin_amdgcn_exp2f(fminf(s[4 * gg + 1], 86.f));
        float p2 = __builtin_amdgcn_exp2f(fminf(s[4 * gg + 2], 86.f));
        float p3 = __builtin_amdgcn_exp2f(fminf(s[4 * gg + 3], 86.f));
        l_sum += (p0 + p1) + (p2 + p3);
        union { unsigned short u[4]; u64 ll; } pkk;
        pkk.u[0] = f2bf(p0); pkk.u[1] = f2bf(p1);
        pkk.u[2] = f2bf(p2); pkk.u[3] = f2bf(p3);
        pk[t][gg] = pkk.ll;
      }
    }
#pragma unroll
    for (int t = 0; t < 2; ++t) {
#pragma unroll
      for (int c = 0; c < 2; ++c) {
        union { u64 q[2]; short8 v; } pf;
        pf.q[0] = pk[t][2 * c];
        pf.q[1] = pk[t][2 * c + 1];
        int cb = we * 8 + t * 4 + c * 2 + hi;
#pragma unroll
        for (int mt = 0; mt < 2; ++mt) {
          int ch = mt * 32 + n;
          short8 af = *(const short8*)&V_ls[VIDX(ch, cb, 0)];
          o_acc[mt] = mfma32(af, pf.v, o_acc[mt]);
        }
      }
    }
    __syncthreads();
  }
  l_sum += __shfl_xor(l_sum, 32);
  if (we == 1) {
    if (hi == 0) lsred[wd * 32 + n] = l_sum;
#pragma unroll
    for (int mt = 0; mt < 2; ++mt)
#pragma unroll
      for (int r = 0; r < 16; ++r) {
        int chl = (r & 3) + 8 * (r >> 2) + 4 * hi;
        Ored[(wd * 64 + mt * 32 + chl) * 34 + n] = o_acc[mt][r];
      }
  }
  __syncthreads();
  if (we == 0) {
    float inv = 1.f / (l_sum + lsred[wd * 32 + n]);
#pragma unroll
    for (int mt = 0; mt < 2; ++mt) {
#pragma unroll
      for (int gg = 0; gg < 4; ++gg) {
        union { unsigned short u[4]; u64 ll; } pkk;
#pragma unroll
        for (int q = 0; q < 4; ++q) {
          int r = gg * 4 + q;
          int chl = q + 8 * gg + 4 * hi;
          float v = (o_acc[mt][r] + Ored[(wd * 64 + mt * 32 + chl) * 34 + n]) * inv;
          pkk.u[q] = f2bf(v);
        }
        *(u64*)&O_l[(wd * 32 + n) * 72 + mt * 32 + gg * 8 + 4 * hi] = pkk.ll;
      }
    }
  }
  __syncthreads();
  for (int it = 0; it < 2; ++it) {
    int l2 = tid + 256 * it;
    int dd = l2 >> 3, seg = l2 & 7;
    *(short8*)(attnT + ((size_t)b * PP + d0 + dd) * CC + h * DH + seg * 8) =
        *(const short8*)&O_l[dd * 72 + seg * 8];
  }
#undef KIDX
#undef VIDX
}

// ------------- Kernel 4: proj GEMM + bias + residual (fp32 out) ------------
// Tile 64p x 64o -> grid 512 = 2 blocks/CU (measured optimum: 1/CU starves
// latency hiding, 32p tiles double weight staging — r5 regression).
// 4 o-tiles sharing one (p0,b) attnT slice stay on the same XCD.
__global__ __launch_bounds__(256) void proj_gemm(
    const unsigned short* __restrict__ attnT, const unsigned short* __restrict__ pwbf,
    const float* __restrict__ projb, const float* __restrict__ x,
    float* __restrict__ out) {
  int bid = blockIdx.x;
  int c8 = bid & 7, rr = bid >> 3;   // rr: 0..63
  int t = rr & 3, base = rr >> 2;    // t: o-tile, base: 0..15
  int p0 = base * 64, b = c8, o0 = t * 64;
  int tid = threadIdx.x;
  int w = tid >> 6, lane = tid & 63, lq = lane >> 4, ln = lane & 15;
  __shared__ unsigned short A_l[64][40];
  __shared__ unsigned short B_l[64][40];
  f32x4 acc[4];
  for (int i = 0; i < 4; ++i) acc[i] = (f32x4){0.f, 0.f, 0.f, 0.f};
  for (int kc = 0; kc < 256; kc += 32) {
    {
      int row = tid >> 2, seg = tid & 3;
      *(short8*)&A_l[row][seg * 8] =
          *(const short8*)(pwbf + (size_t)(o0 + row) * CC + kc + seg * 8);
      *(short8*)&B_l[row][seg * 8] =
          *(const short8*)(attnT + ((size_t)b * PP + p0 + row) * CC + kc + seg * 8);
    }
    __syncthreads();
    short8 af[4];
    for (int i = 0; i < 4; ++i)
      af[i] = *(const short8*)&A_l[i * 16 + ln][lq * 8];
    short8 bfr = *(const short8*)&B_l[w * 16 + ln][lq * 8];
    for (int i = 0; i < 4; ++i) acc[i] = mfma16(af[i], bfr, acc[i]);
    __syncthreads();
  }
  int p = p0 + w * 16 + ln;
  for (int i = 0; i < 4; ++i) {
    for (int r = 0; r < 4; ++r) {
      int o = o0 + i * 16 + lq * 4 + r;
      size_t idx = ((size_t)b * CC + o) * PP + p;
      out[idx] = x[idx] + projb[o] + acc[i][r];
    }
  }
}

// ---------------------------------------------------------------------------
extern "C" void kernel_launch(void* const* d_in, const int* in_sizes, int n_in,
                              void* d_out, int out_size, void* d_ws, size_t ws_size,
                              hipStream_t stream) {
  const float* x = (const float*)d_in[0];
  const float* gamma = (const float*)d_in[1];
  const float* beta = (const float*)d_in[2];
  const float* qkvw = (const float*)d_in[3];
  const float* qkvb = (const float*)d_in[4];
  const float* projw = (const float*)d_in[5];
  const float* projb = (const float*)d_in[6];
  float* out = (float*)d_out;
  char* ws = (char*)d_ws;

  float2* part = (float2*)(ws + 0);                        //  4 KB
  unsigned short* wall = (unsigned short*)(ws + 4210688);  // 512 KB
  unsigned short* pwbf = wall + 768 * 256;
  unsigned short* qb = (unsigned short*)(ws + 4734976);      // 4 MB
  unsigned short* kb = (unsigned short*)(ws + 8929280);      // 4 MB
  unsigned short* vT = (unsigned short*)(ws + 13123584);     // 4 MB
  unsigned short* attnT = (unsigned short*)(ws + 17317888);  // 4 MB

  prep<<<768, 256, 0, stream>>>(x, part, qkvw, projw, wall);
  nqkv<<<768, 256, 0, stream>>>(x, part, gamma, beta, wall, qkvb, qb, kb, vT);
  attn<<<512, 256, 0, stream>>>(qb, kb, vT, attnT);
  proj_gemm<<<512, 256, 0, stream>>>(attnT, pwbf, projb, x, out);
}